// Round 1
// baseline (3858.366 us; speedup 1.0000x reference)
//
#include <hip/hip_runtime.h>
#include <math.h>

#define TS 256
#define BB 1024
#define NQ 8
#define INDIM 128
#define CATDIM 136

// Precompute cos/sin of variational half-angles: trig[w][d][q][2], w=gate(f,i,g,o)
__global__ void qlstm_trig(const float* __restrict__ Pf, const float* __restrict__ Pi,
                           const float* __restrict__ Pg, const float* __restrict__ Po,
                           float* __restrict__ trig) {
    int i = threadIdx.x;
    if (i < 64) {
        int w = i >> 4;
        int dq = i & 15;
        const float* P = (w == 0) ? Pf : (w == 1) ? Pi : (w == 2) ? Pg : Po;
        float ha = 0.5f * P[dq];
        trig[i * 2 + 0] = cosf(ha);
        trig[i * 2 + 1] = sinf(ha);
    }
}

// One block per batch element b; wave w (=tid>>6) simulates gate w (f,i,g,o).
// Lane holds amplitudes k = j*64 + lane, j=0..3. Wire q <-> bit (7-q) of k.
__launch_bounds__(256)
__global__ void qlstm_step(const float* __restrict__ x,
                           const float* __restrict__ Wf, const float* __restrict__ bf,
                           const float* __restrict__ Wi, const float* __restrict__ bi,
                           const float* __restrict__ Wg, const float* __restrict__ bg,
                           const float* __restrict__ Wo, const float* __restrict__ bo,
                           const float* __restrict__ trig,
                           float* __restrict__ out, float* __restrict__ hst,
                           float* __restrict__ cst, int t) {
    int b = blockIdx.x;
    int tid = threadIdx.x;
    int w = tid >> 6;
    int lane = tid & 63;
    int q = lane >> 3;      // output qubit this lane helps compute the angle for
    int kg = lane & 7;      // k-chunk within the 128-dot

    __shared__ float gact[4][8];

    const float* W; const float* bias;
    if (w == 0) { W = Wf; bias = bf; }
    else if (w == 1) { W = Wi; bias = bi; }
    else if (w == 2) { W = Wg; bias = bg; }
    else { W = Wo; bias = bo; }

    const float* Wq = W + q * CATDIM;
    const float* xrow = x + ((size_t)t * BB + b) * INDIM;

    // ---- previous hidden state (zeros at t==0; poison never read) ----
    float h[8];
    if (t == 0) {
        #pragma unroll
        for (int j = 0; j < 8; ++j) h[j] = 0.f;
    } else {
        #pragma unroll
        for (int j = 0; j < 8; ++j) h[j] = hst[b * 8 + j];
    }

    // ---- angles: x-part dot (8 lanes x 16 MACs, shuffle-reduced) + h-part + bias ----
    const float4* x4 = (const float4*)(xrow + kg * 16);
    const float4* w4 = (const float4*)(Wq + kg * 16);
    float partial = 0.f;
    #pragma unroll
    for (int c4 = 0; c4 < 4; ++c4) {
        float4 xv = x4[c4];
        float4 wv = w4[c4];
        partial += xv.x * wv.x + xv.y * wv.y + xv.z * wv.z + xv.w * wv.w;
    }
    partial += __shfl_xor(partial, 1);
    partial += __shfl_xor(partial, 2);
    partial += __shfl_xor(partial, 4);

    float ang = partial + bias[q];
    #pragma unroll
    for (int j = 0; j < 8; ++j) ang += Wq[INDIM + j] * h[j];

    // broadcast all 8 angles to every lane; half-angle trig
    float cq[8], sq[8];
    #pragma unroll
    for (int qq = 0; qq < 8; ++qq) {
        float a = 0.5f * __shfl(ang, qq * 8);
        __sincosf(a, &sq[qq], &cq[qq]);
    }

    // ---- build product state after RX encoding: amp[k] = (-i)^pc(k) * prod(factors) ----
    float re[4], im[4];
    #pragma unroll
    for (int j = 0; j < 4; ++j) {
        int k = j * 64 + lane;
        float mag = 1.f;
        #pragma unroll
        for (int qq = 0; qq < 8; ++qq) {
            mag *= ((k >> (7 - qq)) & 1) ? sq[qq] : cq[qq];
        }
        int p = __popc(k) & 3;
        re[j] = (p == 0) ? mag : ((p == 2) ? -mag : 0.f);
        im[j] = (p == 1) ? -mag : ((p == 3) ? mag : 0.f);
    }

    // ---- variational layers: RY (real rotation) + CNOT chain, applied to re & im ----
    const float* tg = trig + w * 32;
    #pragma unroll
    for (int d = 0; d < 2; ++d) {
        #pragma unroll
        for (int qq = 0; qq < 8; ++qq) {
            float cp = tg[(d * 8 + qq) * 2 + 0];
            float sp = tg[(d * 8 + qq) * 2 + 1];
            int bt = 7 - qq;
            if (bt <= 5) {                      // cross-lane bit
                float sv = ((lane >> bt) & 1) ? sp : -sp;
                #pragma unroll
                for (int j = 0; j < 4; ++j) {
                    float pr = __shfl_xor(re[j], 1 << bt);
                    float pi = __shfl_xor(im[j], 1 << bt);
                    re[j] = cp * re[j] + sv * pr;
                    im[j] = cp * im[j] + sv * pi;
                }
            } else if (bt == 6) {               // pairs (j0,j1),(j2,j3)
                float tr;
                tr = re[0]; re[0] = cp * tr - sp * re[1]; re[1] = sp * tr + cp * re[1];
                tr = re[2]; re[2] = cp * tr - sp * re[3]; re[3] = sp * tr + cp * re[3];
                tr = im[0]; im[0] = cp * tr - sp * im[1]; im[1] = sp * tr + cp * im[1];
                tr = im[2]; im[2] = cp * tr - sp * im[3]; im[3] = sp * tr + cp * im[3];
            } else {                            // bt==7: pairs (j0,j2),(j1,j3)
                float tr;
                tr = re[0]; re[0] = cp * tr - sp * re[2]; re[2] = sp * tr + cp * re[2];
                tr = re[1]; re[1] = cp * tr - sp * re[3]; re[3] = sp * tr + cp * re[3];
                tr = im[0]; im[0] = cp * tr - sp * im[2]; im[2] = sp * tr + cp * im[2];
                tr = im[1]; im[1] = cp * tr - sp * im[3]; im[3] = sp * tr + cp * im[3];
            }
        }
        // CNOT chain c=0..6 (control bit 7-c, target bit 6-c)
        // c=0: control j-bit1, target j-bit0 -> swap slots 2,3
        { float tr = re[2]; re[2] = re[3]; re[3] = tr;
          float ti = im[2]; im[2] = im[3]; im[3] = ti; }
        // c=1: control j-bit0, target lane bit5 -> slots 1,3 swap across lanes
        re[1] = __shfl_xor(re[1], 32); im[1] = __shfl_xor(im[1], 32);
        re[3] = __shfl_xor(re[3], 32); im[3] = __shfl_xor(im[3], 32);
        // c=2..6: both bits in lane index
        #pragma unroll
        for (int c = 2; c <= 6; ++c) {
            int cb = 7 - c;
            int tmask = 1 << (6 - c);
            bool ctrl = (lane >> cb) & 1;
            #pragma unroll
            for (int j = 0; j < 4; ++j) {
                float pr = __shfl_xor(re[j], tmask);
                float pi = __shfl_xor(im[j], tmask);
                if (ctrl) { re[j] = pr; im[j] = pi; }
            }
        }
    }

    // ---- probabilities and PauliZ expectations ----
    float p0 = re[0] * re[0] + im[0] * im[0];
    float p1 = re[1] * re[1] + im[1] * im[1];
    float p2 = re[2] * re[2] + im[2] * im[2];
    float p3 = re[3] * re[3] + im[3] * im[3];
    float Pt = p0 + p1 + p2 + p3;
    float e[8];
    e[0] = p0 + p1 - p2 - p3;   // wire 0 <-> bit7 (j bit1)
    e[1] = p0 - p1 + p2 - p3;   // wire 1 <-> bit6 (j bit0)
    #pragma unroll
    for (int qq = 2; qq < 8; ++qq) {
        int bt = 7 - qq;
        e[qq] = ((lane >> bt) & 1) ? -Pt : Pt;
    }
    #pragma unroll
    for (int qq = 0; qq < 8; ++qq) {
        #pragma unroll
        for (int m = 1; m < 64; m <<= 1)
            e[qq] += __shfl_xor(e[qq], m);
    }

    // ---- gate nonlinearity ----
    float act[8];
    #pragma unroll
    for (int qq = 0; qq < 8; ++qq) {
        if (w == 2) {                           // g gate: tanh
            float t2 = __expf(2.f * e[qq]);
            act[qq] = (t2 - 1.f) / (t2 + 1.f);
        } else {                                // f,i,o: sigmoid
            act[qq] = 1.f / (1.f + __expf(-e[qq]));
        }
    }
    if (lane == 0) {
        #pragma unroll
        for (int qq = 0; qq < 8; ++qq) gact[w][qq] = act[qq];
    }
    __syncthreads();

    // ---- LSTM cell update (8 threads) ----
    if (tid < 8) {
        int qq = tid;
        float fv = gact[0][qq], iv = gact[1][qq], gv = gact[2][qq], ov = gact[3][qq];
        float cv = (t == 0) ? 0.f : cst[b * 8 + qq];
        cv = fv * cv + iv * gv;
        float e2 = __expf(2.f * cv);
        float hv = ov * ((e2 - 1.f) / (e2 + 1.f));
        cst[b * 8 + qq] = cv;
        hst[b * 8 + qq] = hv;
        out[((size_t)t * BB + b) * 8 + qq] = hv;
    }
}

extern "C" void kernel_launch(void* const* d_in, const int* in_sizes, int n_in,
                              void* d_out, int out_size, void* d_ws, size_t ws_size,
                              hipStream_t stream) {
    const float* x  = (const float*)d_in[0];
    const float* Wf = (const float*)d_in[1];
    const float* bf = (const float*)d_in[2];
    const float* Pf = (const float*)d_in[3];
    const float* Wi = (const float*)d_in[4];
    const float* bi = (const float*)d_in[5];
    const float* Pi = (const float*)d_in[6];
    const float* Wg = (const float*)d_in[7];
    const float* bg = (const float*)d_in[8];
    const float* Pg = (const float*)d_in[9];
    const float* Wo = (const float*)d_in[10];
    const float* bo = (const float*)d_in[11];
    const float* Po = (const float*)d_in[12];

    float* out = (float*)d_out;
    float* hst = out + (size_t)TS * BB * NQ;   // hx lives in d_out tail
    float* cst = hst + (size_t)BB * NQ;        // cx follows
    float* trig = (float*)d_ws;                // 128 floats

    qlstm_trig<<<1, 64, 0, stream>>>(Pf, Pi, Pg, Po, trig);
    for (int t = 0; t < TS; ++t) {
        qlstm_step<<<BB, 256, 0, stream>>>(x, Wf, bf, Wi, bi, Wg, bg, Wo, bo,
                                           trig, out, hst, cst, t);
    }
}

// Round 2
// 1578.014 us; speedup vs baseline: 2.4451x; 2.4451x over previous
//
#include <hip/hip_runtime.h>
#include <math.h>

#define TS 256
#define BB 1024
#define NQ 8
#define INDIM 128
#define CATDIM 136

// One block = one batch element, looping all T=256 LSTM steps internally.
// Wave w (=tid>>6) simulates gate w (f,i,g,o). Lane holds amplitudes
// k = j*64 + lane, j=0..3. Wire q <-> bit (7-q) of k.
__launch_bounds__(256, 4)
__global__ void qlstm_fused(const float* __restrict__ x,
    const float* __restrict__ Wf, const float* __restrict__ bf, const float* __restrict__ Pf,
    const float* __restrict__ Wi, const float* __restrict__ bi, const float* __restrict__ Pi,
    const float* __restrict__ Wg, const float* __restrict__ bg, const float* __restrict__ Pg,
    const float* __restrict__ Wo, const float* __restrict__ bo, const float* __restrict__ Po,
    float* __restrict__ out, float* __restrict__ hst, float* __restrict__ cst)
{
    const int b = blockIdx.x;
    const int tid = threadIdx.x;
    const int w = tid >> 6;
    const int lane = tid & 63;
    const int q = lane >> 3;      // qubit whose angle this lane helps compute
    const int kg = lane & 7;      // chunk of the 128-wide x dot

    __shared__ float gact[4][8];
    __shared__ float hsh[8];
    __shared__ float csh[8];

    const float* W; const float* bias; const float* P;
    if (w == 0)      { W = Wf; bias = bf; P = Pf; }
    else if (w == 1) { W = Wi; bias = bi; P = Pi; }
    else if (w == 2) { W = Wg; bias = bg; P = Pg; }
    else             { W = Wo; bias = bo; P = Po; }

    // ---- hoisted: variational trig as wave-uniform scalars ----
    float CP[16], SP[16];
    #pragma unroll
    for (int i2 = 0; i2 < 16; ++i2) {
        float ha = 0.5f * P[i2];
        float cv = cosf(ha), sv = sinf(ha);
        CP[i2] = __int_as_float(__builtin_amdgcn_readfirstlane(__float_as_int(cv)));
        SP[i2] = __int_as_float(__builtin_amdgcn_readfirstlane(__float_as_int(sv)));
    }

    // ---- hoisted: weights for this lane's qubit ----
    const float* Wq = W + q * CATDIM;
    float4 wx[4];
    #pragma unroll
    for (int c4 = 0; c4 < 4; ++c4)
        wx[c4] = *(const float4*)(Wq + kg * 16 + c4 * 4);
    float wh[8];
    #pragma unroll
    for (int j = 0; j < 8; ++j) wh[j] = Wq[INDIM + j];
    const float bq = bias[q];

    // ---- hoisted: RX product-state phase signs: (-i)^popc(k) ----
    float rsg[4], isg[4];
    #pragma unroll
    for (int j = 0; j < 4; ++j) {
        int p = __popc(j * 64 + lane) & 3;
        rsg[j] = (p == 0) ? 1.f : (p == 2) ? -1.f : 0.f;
        isg[j] = (p == 1) ? -1.f : (p == 3) ? 1.f : 0.f;
    }

    // ---- hoisted: gray-code CNOT-chain bpermute addresses ----
    const int ga = (lane ^ (lane >> 1)) << 2;
    const int gb = ga ^ 128;

    if (tid < 8) { hsh[tid] = 0.f; csh[tid] = 0.f; }
    __syncthreads();

    // prefetch x row for t=0
    float4 xv[4];
    {
        const float* xr = x + (size_t)b * INDIM + kg * 16;
        #pragma unroll
        for (int c4 = 0; c4 < 4; ++c4) xv[c4] = *(const float4*)(xr + c4 * 4);
    }

    for (int t = 0; t < TS; ++t) {
        // ---- x-part of angle (uses prefetched row) ----
        float partial =
            xv[0].x*wx[0].x + xv[0].y*wx[0].y + xv[0].z*wx[0].z + xv[0].w*wx[0].w +
            xv[1].x*wx[1].x + xv[1].y*wx[1].y + xv[1].z*wx[1].z + xv[1].w*wx[1].w +
            xv[2].x*wx[2].x + xv[2].y*wx[2].y + xv[2].z*wx[2].z + xv[2].w*wx[2].w +
            xv[3].x*wx[3].x + xv[3].y*wx[3].y + xv[3].z*wx[3].z + xv[3].w*wx[3].w;

        // issue prefetch for t+1 (hides under the quantum sim)
        float4 xn[4];
        {
            int t2 = (t + 1 < TS) ? t + 1 : t;
            const float* xr = x + ((size_t)t2 * BB + b) * INDIM + kg * 16;
            #pragma unroll
            for (int c4 = 0; c4 < 4; ++c4) xn[c4] = *(const float4*)(xr + c4 * 4);
        }

        partial += __shfl_xor(partial, 1, 64);
        partial += __shfl_xor(partial, 2, 64);
        partial += __shfl_xor(partial, 4, 64);

        float4 h01 = *(const float4*)&hsh[0];
        float4 h23 = *(const float4*)&hsh[4];
        float ang = partial + bq
            + wh[0]*h01.x + wh[1]*h01.y + wh[2]*h01.z + wh[3]*h01.w
            + wh[4]*h23.x + wh[5]*h23.y + wh[6]*h23.z + wh[7]*h23.w;

        // broadcast all 8 angles; half-angle trig
        float cq[8], sq[8];
        #pragma unroll
        for (int qq = 0; qq < 8; ++qq) {
            float a = 0.5f * __shfl(ang, qq * 8, 64);
            __sincosf(a, &sq[qq], &cq[qq]);
        }

        // ---- RX product state ----
        float m = ((lane >> 5) & 1) ? sq[2] : cq[2];
        m *= ((lane >> 4) & 1) ? sq[3] : cq[3];
        m *= ((lane >> 3) & 1) ? sq[4] : cq[4];
        m *= ((lane >> 2) & 1) ? sq[5] : cq[5];
        m *= ((lane >> 1) & 1) ? sq[6] : cq[6];
        m *= (lane & 1) ? sq[7] : cq[7];
        float f0 = cq[0]*cq[1], f1 = cq[0]*sq[1], f2 = sq[0]*cq[1], f3 = sq[0]*sq[1];
        float m0 = m*f0, m1 = m*f1, m2 = m*f2, m3 = m*f3;
        float re[4], im[4];
        re[0] = rsg[0]*m0; im[0] = isg[0]*m0;
        re[1] = rsg[1]*m1; im[1] = isg[1]*m1;
        re[2] = rsg[2]*m2; im[2] = isg[2]*m2;
        re[3] = rsg[3]*m3; im[3] = isg[3]*m3;

        // ---- variational layers ----
        #pragma unroll
        for (int d = 0; d < 2; ++d) {
            { // qq=0, bit7: register pairs (0,2),(1,3)
                float cp = CP[d*8+0], sp = SP[d*8+0], tr;
                tr=re[0]; re[0]=cp*tr-sp*re[2]; re[2]=sp*tr+cp*re[2];
                tr=re[1]; re[1]=cp*tr-sp*re[3]; re[3]=sp*tr+cp*re[3];
                tr=im[0]; im[0]=cp*tr-sp*im[2]; im[2]=sp*tr+cp*im[2];
                tr=im[1]; im[1]=cp*tr-sp*im[3]; im[3]=sp*tr+cp*im[3];
            }
            { // qq=1, bit6: register pairs (0,1),(2,3)
                float cp = CP[d*8+1], sp = SP[d*8+1], tr;
                tr=re[0]; re[0]=cp*tr-sp*re[1]; re[1]=sp*tr+cp*re[1];
                tr=re[2]; re[2]=cp*tr-sp*re[3]; re[3]=sp*tr+cp*re[3];
                tr=im[0]; im[0]=cp*tr-sp*im[1]; im[1]=sp*tr+cp*im[1];
                tr=im[2]; im[2]=cp*tr-sp*im[3]; im[3]=sp*tr+cp*im[3];
            }
            #pragma unroll
            for (int qq = 2; qq < 8; ++qq) {   // cross-lane bits 5..0
                int bt = 7 - qq;
                float cp = CP[d*8+qq], sp = SP[d*8+qq];
                float sv = ((lane >> bt) & 1) ? sp : -sp;
                #pragma unroll
                for (int j = 0; j < 4; ++j) {
                    float pr = __shfl_xor(re[j], 1 << bt, 64);
                    float pi = __shfl_xor(im[j], 1 << bt, 64);
                    re[j] = cp*re[j] + sv*pr;
                    im[j] = cp*im[j] + sv*pi;
                }
            }
            // CNOT chain == gray-code permutation: out[k'] = in[k' ^ (k'>>1)]
            {
                float nr0 = __int_as_float(__builtin_amdgcn_ds_bpermute(ga, __float_as_int(re[0])));
                float nr1 = __int_as_float(__builtin_amdgcn_ds_bpermute(gb, __float_as_int(re[1])));
                float nr2 = __int_as_float(__builtin_amdgcn_ds_bpermute(ga, __float_as_int(re[3])));
                float nr3 = __int_as_float(__builtin_amdgcn_ds_bpermute(gb, __float_as_int(re[2])));
                float ni0 = __int_as_float(__builtin_amdgcn_ds_bpermute(ga, __float_as_int(im[0])));
                float ni1 = __int_as_float(__builtin_amdgcn_ds_bpermute(gb, __float_as_int(im[1])));
                float ni2 = __int_as_float(__builtin_amdgcn_ds_bpermute(ga, __float_as_int(im[3])));
                float ni3 = __int_as_float(__builtin_amdgcn_ds_bpermute(gb, __float_as_int(im[2])));
                re[0]=nr0; re[1]=nr1; re[2]=nr2; re[3]=nr3;
                im[0]=ni0; im[1]=ni1; im[2]=ni2; im[3]=ni3;
            }
        }

        // ---- probabilities and per-lane qubit contributions ----
        float p0 = re[0]*re[0] + im[0]*im[0];
        float p1 = re[1]*re[1] + im[1]*im[1];
        float p2 = re[2]*re[2] + im[2]*im[2];
        float p3 = re[3]*re[3] + im[3]*im[3];
        float Pt = (p0 + p1) + (p2 + p3);
        float nPt = -Pt;
        float v0 = p0 + p1 - p2 - p3;            // qubit0 (bit7 = j bit1)
        float v1 = p0 - p1 + p2 - p3;            // qubit1 (bit6 = j bit0)
        float v2 = ((lane >> 5) & 1) ? nPt : Pt;
        float v3 = ((lane >> 4) & 1) ? nPt : Pt;
        float v4 = ((lane >> 3) & 1) ? nPt : Pt;
        float v5 = ((lane >> 2) & 1) ? nPt : Pt;
        float v6 = ((lane >> 1) & 1) ? nPt : Pt;
        float v7 = (lane & 1) ? nPt : Pt;

        // ---- 8-value 64-lane reduction in 10 shuffles ----
        {
            int c0 = lane & 1;
            float s, r;
            s = c0 ? v0 : v4; r = __shfl_xor(s, 1, 64); v0 = (c0 ? v4 : v0) + r;
            s = c0 ? v1 : v5; r = __shfl_xor(s, 1, 64); v1 = (c0 ? v5 : v1) + r;
            s = c0 ? v2 : v6; r = __shfl_xor(s, 1, 64); v2 = (c0 ? v6 : v2) + r;
            s = c0 ? v3 : v7; r = __shfl_xor(s, 1, 64); v3 = (c0 ? v7 : v3) + r;
            int c1 = lane & 2;
            s = c1 ? v0 : v2; r = __shfl_xor(s, 2, 64); v0 = (c1 ? v2 : v0) + r;
            s = c1 ? v1 : v3; r = __shfl_xor(s, 2, 64); v1 = (c1 ? v3 : v1) + r;
            int c2 = lane & 4;
            s = c2 ? v0 : v1; r = __shfl_xor(s, 4, 64); v0 = (c2 ? v1 : v0) + r;
            v0 += __shfl_xor(v0, 8, 64);
            v0 += __shfl_xor(v0, 16, 64);
            v0 += __shfl_xor(v0, 32, 64);
        }
        // lane l now holds S[q] with q = 4*l0 + 2*l1 + l2

        if (lane < 8) {
            int qr = ((lane & 1) << 2) | (lane & 2) | ((lane >> 2) & 1);
            float a;
            if (w == 2) { float e2 = __expf(2.f * v0); a = (e2 - 1.f) / (e2 + 1.f); }
            else        { a = 1.f / (1.f + __expf(-v0)); }
            gact[w][qr] = a;
        }
        __syncthreads();

        if (tid < 8) {
            float fv = gact[0][tid], iv = gact[1][tid], gv = gact[2][tid], ov = gact[3][tid];
            float cv = csh[tid];
            cv = fv * cv + iv * gv;
            float e2 = __expf(2.f * cv);
            float hv = ov * ((e2 - 1.f) / (e2 + 1.f));
            csh[tid] = cv; hsh[tid] = hv;
            out[((size_t)t * BB + b) * NQ + tid] = hv;
        }
        __syncthreads();

        xv[0] = xn[0]; xv[1] = xn[1]; xv[2] = xn[2]; xv[3] = xn[3];
    }

    if (tid < 8) {
        hst[b * NQ + tid] = hsh[tid];
        cst[b * NQ + tid] = csh[tid];
    }
}

extern "C" void kernel_launch(void* const* d_in, const int* in_sizes, int n_in,
                              void* d_out, int out_size, void* d_ws, size_t ws_size,
                              hipStream_t stream) {
    const float* x  = (const float*)d_in[0];
    const float* Wf = (const float*)d_in[1];
    const float* bf = (const float*)d_in[2];
    const float* Pf = (const float*)d_in[3];
    const float* Wi = (const float*)d_in[4];
    const float* bi = (const float*)d_in[5];
    const float* Pi = (const float*)d_in[6];
    const float* Wg = (const float*)d_in[7];
    const float* bg = (const float*)d_in[8];
    const float* Pg = (const float*)d_in[9];
    const float* Wo = (const float*)d_in[10];
    const float* bo = (const float*)d_in[11];
    const float* Po = (const float*)d_in[12];

    float* out = (float*)d_out;
    float* hst = out + (size_t)TS * BB * NQ;   // hx in d_out tail
    float* cst = hst + (size_t)BB * NQ;        // cx follows

    qlstm_fused<<<BB, 256, 0, stream>>>(x, Wf, bf, Pf, Wi, bi, Pi,
                                        Wg, bg, Pg, Wo, bo, Po,
                                        out, hst, cst);
}

// Round 3
// 689.269 us; speedup vs baseline: 5.5978x; 2.2894x over previous
//
#include <hip/hip_runtime.h>
#include <math.h>

#define TS 256
#define BB 1024
#define NQ 8
#define INDIM 128
#define CATDIM 136

__device__ __forceinline__ float dpp_xor1(float v) {
    return __int_as_float(__builtin_amdgcn_mov_dpp(__float_as_int(v), 0xB1, 0xF, 0xF, true));
}
__device__ __forceinline__ float dpp_xor2(float v) {
    return __int_as_float(__builtin_amdgcn_mov_dpp(__float_as_int(v), 0x4E, 0xF, 0xF, true));
}
__device__ __forceinline__ float rdlane(float v, int l) {
    return __int_as_float(__builtin_amdgcn_readlane(__float_as_int(v), l));
}
__device__ __forceinline__ float rdfirst(float v) {
    return __int_as_float(__builtin_amdgcn_readfirstlane(__float_as_int(v)));
}
#define CMUL(zr, zi, ar, ai, br, bi) { float _t = (ar)*(br) - (ai)*(bi); zi = (ar)*(bi) + (ai)*(br); zr = _t; }

// One block = one batch element, all T=256 steps in-kernel.
// Wave w = gate (f,i,g,o). Lane holds amps k = j*64+lane, j=0..3.
// Wire q <-> bit (7-q). Algebraic folds:
//   - RX + RY layer-0 -> single-qubit product state
//   - CNOT chain #1 (gray code g(k)=k^(k>>1)) -> folded into build selectors
//   - CNOT chain #2 -> folded into measurement signs (prefix parities)
// Only RY layer-1 is applied explicitly.
__launch_bounds__(256, 4)
__global__ void qlstm_fused(const float* __restrict__ x,
    const float* __restrict__ Wf, const float* __restrict__ bf, const float* __restrict__ Pf,
    const float* __restrict__ Wi, const float* __restrict__ bi, const float* __restrict__ Pi,
    const float* __restrict__ Wg, const float* __restrict__ bg, const float* __restrict__ Pg,
    const float* __restrict__ Wo, const float* __restrict__ bo, const float* __restrict__ Po,
    float* __restrict__ out, float* __restrict__ hst, float* __restrict__ cst)
{
    const int b = blockIdx.x;
    const int tid = threadIdx.x;
    const int w = tid >> 6;
    const int lane = tid & 63;
    const int q = lane >> 3;
    const int kg = lane & 7;

    __shared__ float gact[4][8];
    __shared__ __align__(16) float hsh[8];
    __shared__ float csh[8];

    const float* W; const float* bias; const float* P;
    if (w == 0)      { W = Wf; bias = bf; P = Pf; }
    else if (w == 1) { W = Wi; bias = bi; P = Pi; }
    else if (w == 2) { W = Wg; bias = bg; P = Pg; }
    else             { W = Wo; bias = bo; P = Po; }

    // variational trig: layer0 stays VGPR (feeds per-lane selects), layer1 -> SGPR
    float cp0[8], sp0[8], cp1[8], sp1[8];
    #pragma unroll
    for (int qq = 0; qq < 8; ++qq) {
        float h0 = 0.5f * P[qq];
        cp0[qq] = cosf(h0); sp0[qq] = sinf(h0);
        float h1 = 0.5f * P[8 + qq];
        cp1[qq] = rdfirst(cosf(h1)); sp1[qq] = rdfirst(sinf(h1));
    }

    // weights for this lane's qubit
    const float* Wq = W + q * CATDIM;
    float4 wx[4];
    #pragma unroll
    for (int c4 = 0; c4 < 4; ++c4)
        wx[c4] = *(const float4*)(Wq + kg * 16 + c4 * 4);
    float wh[8];
    #pragma unroll
    for (int j = 0; j < 8; ++j) wh[j] = Wq[INDIM + j];
    const float bq = bias[q];

    // hoisted lane bits, gray-code selectors, measurement sign prefixes
    const int l0 = lane & 1, l1 = (lane >> 1) & 1, l2b = (lane >> 2) & 1;
    const int l3 = (lane >> 3) & 1, l4 = (lane >> 4) & 1, l5 = (lane >> 5) & 1;
    const int s0 = l0 ^ l1, s1 = l1 ^ l2b, s2 = l2b ^ l3, s3 = l3 ^ l4, s4 = l4 ^ l5;
    int pr_ = l5;            const float sg2 = pr_ ? -1.f : 1.f;
    pr_ ^= l4;               const float sg3 = pr_ ? -1.f : 1.f;
    pr_ ^= l3;               const float sg4 = pr_ ? -1.f : 1.f;
    pr_ ^= l2b;              const float sg5 = pr_ ? -1.f : 1.f;
    pr_ ^= l1;               const float sg6 = pr_ ? -1.f : 1.f;
    pr_ ^= l0;               const float sg7 = pr_ ? -1.f : 1.f;

    if (tid < 8) { hsh[tid] = 0.f; csh[tid] = 0.f; }
    __syncthreads();

    float4 xv[4];
    {
        const float* xr = x + (size_t)b * INDIM + kg * 16;
        #pragma unroll
        for (int c4 = 0; c4 < 4; ++c4) xv[c4] = *(const float4*)(xr + c4 * 4);
    }

    for (int t = 0; t < TS; ++t) {
        // ---- angle: x-dot ----
        float partial =
            xv[0].x*wx[0].x + xv[0].y*wx[0].y + xv[0].z*wx[0].z + xv[0].w*wx[0].w +
            xv[1].x*wx[1].x + xv[1].y*wx[1].y + xv[1].z*wx[1].z + xv[1].w*wx[1].w +
            xv[2].x*wx[2].x + xv[2].y*wx[2].y + xv[2].z*wx[2].z + xv[2].w*wx[2].w +
            xv[3].x*wx[3].x + xv[3].y*wx[3].y + xv[3].z*wx[3].z + xv[3].w*wx[3].w;

        float4 xn[4];
        {
            int t2 = (t + 1 < TS) ? t + 1 : t;
            const float* xr = x + ((size_t)t2 * BB + b) * INDIM + kg * 16;
            #pragma unroll
            for (int c4 = 0; c4 < 4; ++c4) xn[c4] = *(const float4*)(xr + c4 * 4);
        }

        partial += dpp_xor1(partial);
        partial += dpp_xor2(partial);
        partial += __shfl_xor(partial, 4, 64);

        float4 h01 = *(const float4*)&hsh[0];
        float4 h23 = *(const float4*)&hsh[4];
        float ang = partial + bq
            + wh[0]*h01.x + wh[1]*h01.y + wh[2]*h01.z + wh[3]*h01.w
            + wh[4]*h23.x + wh[5]*h23.y + wh[6]*h23.z + wh[7]*h23.w;

        // ---- broadcast angles, half-angle trig ----
        float cqv[8], sqv[8];
        #pragma unroll
        for (int qq = 0; qq < 8; ++qq) {
            float a = 0.5f * rdlane(ang, qq * 8);
            __sincosf(a, &sqv[qq], &cqv[qq]);
        }

        // ---- product state (RX*RY0) with gray-code reindex folded in ----
        // factor(wire, sel): sel ? (sp0*c, -cp0*s) : (cp0*c, sp0*s)
        float Mr, Mi;
        {   // bit0 -> wire7, sel s0
            Mr = (s0 ? sp0[7] : cp0[7]) * cqv[7];
            Mi = (s0 ? -cp0[7] : sp0[7]) * sqv[7];
        }
        {   // bit1 -> wire6, sel s1
            float fr = (s1 ? sp0[6] : cp0[6]) * cqv[6];
            float fi = (s1 ? -cp0[6] : sp0[6]) * sqv[6];
            CMUL(Mr, Mi, Mr, Mi, fr, fi);
        }
        {   // bit2 -> wire5, sel s2
            float fr = (s2 ? sp0[5] : cp0[5]) * cqv[5];
            float fi = (s2 ? -cp0[5] : sp0[5]) * sqv[5];
            CMUL(Mr, Mi, Mr, Mi, fr, fi);
        }
        {   // bit3 -> wire4, sel s3
            float fr = (s3 ? sp0[4] : cp0[4]) * cqv[4];
            float fi = (s3 ? -cp0[4] : sp0[4]) * sqv[4];
            CMUL(Mr, Mi, Mr, Mi, fr, fi);
        }
        {   // bit4 -> wire3, sel s4
            float fr = (s4 ? sp0[3] : cp0[3]) * cqv[3];
            float fi = (s4 ? -cp0[3] : sp0[3]) * sqv[3];
            CMUL(Mr, Mi, Mr, Mi, fr, fi);
        }
        // bit5 -> wire2, sel l5^j0: Ga (j even), Gb (j odd)
        float gar = (l5 ? sp0[2] : cp0[2]) * cqv[2];
        float gai = (l5 ? -cp0[2] : sp0[2]) * sqv[2];
        float gbr = (l5 ? cp0[2] : sp0[2]) * cqv[2];
        float gbi = (l5 ? sp0[2] : -cp0[2]) * sqv[2];
        float MGar, MGai, MGbr, MGbi;
        CMUL(MGar, MGai, Mr, Mi, gar, gai);
        CMUL(MGbr, MGbi, Mr, Mi, gbr, gbi);
        // wires 1 (bit6, sel j0^j1) and 0 (bit7, sel j1), lane-uniform
        float a1r = cp0[1]*cqv[1], a1i = sp0[1]*sqv[1];
        float b1r = sp0[1]*cqv[1], b1i = -cp0[1]*sqv[1];
        float a0r = cp0[0]*cqv[0], a0i = sp0[0]*sqv[0];
        float b0r = sp0[0]*cqv[0], b0i = -cp0[0]*sqv[0];
        float h00r, h00i, h10r, h10i, h11r, h11i, h01r, h01i;
        CMUL(h00r, h00i, a1r, a1i, a0r, a0i);
        CMUL(h10r, h10i, b1r, b1i, a0r, a0i);
        CMUL(h11r, h11i, b1r, b1i, b0r, b0i);
        CMUL(h01r, h01i, a1r, a1i, b0r, b0i);
        float re[4], im[4];
        CMUL(re[0], im[0], MGar, MGai, h00r, h00i);
        CMUL(re[1], im[1], MGbr, MGbi, h10r, h10i);
        CMUL(re[2], im[2], MGar, MGai, h11r, h11i);
        CMUL(re[3], im[3], MGbr, MGbi, h01r, h01i);

        // ---- RY layer 1 ----
        {   // wire0 (bit7): pairs (0,2),(1,3)
            float cp = cp1[0], sp = sp1[0], tr;
            tr=re[0]; re[0]=cp*tr-sp*re[2]; re[2]=sp*tr+cp*re[2];
            tr=re[1]; re[1]=cp*tr-sp*re[3]; re[3]=sp*tr+cp*re[3];
            tr=im[0]; im[0]=cp*tr-sp*im[2]; im[2]=sp*tr+cp*im[2];
            tr=im[1]; im[1]=cp*tr-sp*im[3]; im[3]=sp*tr+cp*im[3];
        }
        {   // wire1 (bit6): pairs (0,1),(2,3)
            float cp = cp1[1], sp = sp1[1], tr;
            tr=re[0]; re[0]=cp*tr-sp*re[1]; re[1]=sp*tr+cp*re[1];
            tr=re[2]; re[2]=cp*tr-sp*re[3]; re[3]=sp*tr+cp*re[3];
            tr=im[0]; im[0]=cp*tr-sp*im[1]; im[1]=sp*tr+cp*im[1];
            tr=im[2]; im[2]=cp*tr-sp*im[3]; im[3]=sp*tr+cp*im[3];
        }
        {   // wire2 (bit5, mask32)
            float cp = cp1[2], sp = sp1[2];
            float sv = l5 ? sp : -sp;
            #pragma unroll
            for (int j = 0; j < 4; ++j) {
                float pr = __shfl_xor(re[j], 32, 64);
                float pi = __shfl_xor(im[j], 32, 64);
                re[j] = cp*re[j] + sv*pr; im[j] = cp*im[j] + sv*pi;
            }
        }
        {   // wire3 (bit4, mask16)
            float cp = cp1[3], sp = sp1[3];
            float sv = l4 ? sp : -sp;
            #pragma unroll
            for (int j = 0; j < 4; ++j) {
                float pr = __shfl_xor(re[j], 16, 64);
                float pi = __shfl_xor(im[j], 16, 64);
                re[j] = cp*re[j] + sv*pr; im[j] = cp*im[j] + sv*pi;
            }
        }
        {   // wire4 (bit3, mask8)
            float cp = cp1[4], sp = sp1[4];
            float sv = l3 ? sp : -sp;
            #pragma unroll
            for (int j = 0; j < 4; ++j) {
                float pr = __shfl_xor(re[j], 8, 64);
                float pi = __shfl_xor(im[j], 8, 64);
                re[j] = cp*re[j] + sv*pr; im[j] = cp*im[j] + sv*pi;
            }
        }
        {   // wire5 (bit2, mask4)
            float cp = cp1[5], sp = sp1[5];
            float sv = l2b ? sp : -sp;
            #pragma unroll
            for (int j = 0; j < 4; ++j) {
                float pr = __shfl_xor(re[j], 4, 64);
                float pi = __shfl_xor(im[j], 4, 64);
                re[j] = cp*re[j] + sv*pr; im[j] = cp*im[j] + sv*pi;
            }
        }
        {   // wire6 (bit1, mask2) via DPP
            float cp = cp1[6], sp = sp1[6];
            float sv = l1 ? sp : -sp;
            #pragma unroll
            for (int j = 0; j < 4; ++j) {
                float pr = dpp_xor2(re[j]);
                float pi = dpp_xor2(im[j]);
                re[j] = cp*re[j] + sv*pr; im[j] = cp*im[j] + sv*pi;
            }
        }
        {   // wire7 (bit0, mask1) via DPP
            float cp = cp1[7], sp = sp1[7];
            float sv = l0 ? sp : -sp;
            #pragma unroll
            for (int j = 0; j < 4; ++j) {
                float pr = dpp_xor1(re[j]);
                float pi = dpp_xor1(im[j]);
                re[j] = cp*re[j] + sv*pr; im[j] = cp*im[j] + sv*pi;
            }
        }

        // ---- measurement, CNOT chain #2 folded into signs ----
        float p0 = re[0]*re[0] + im[0]*im[0];
        float p1 = re[1]*re[1] + im[1]*im[1];
        float p2 = re[2]*re[2] + im[2]*im[2];
        float p3 = re[3]*re[3] + im[3]*im[3];
        float v0 = (p0 + p1) - (p2 + p3);        // wire0
        float D  = (p0 - p1) - (p2 - p3);        // shared combo, sign (-1)^(j0^j1)
        float v1 = D;
        float v2 = sg2 * D;
        float v3 = sg3 * D;
        float v4 = sg4 * D;
        float v5 = sg5 * D;
        float v6 = sg6 * D;
        float v7 = sg7 * D;

        // ---- 8-value 64-lane reduction ----
        {
            int c0 = lane & 1;
            float s, r;
            s = c0 ? v0 : v4; r = dpp_xor1(s); v0 = (c0 ? v4 : v0) + r;
            s = c0 ? v1 : v5; r = dpp_xor1(s); v1 = (c0 ? v5 : v1) + r;
            s = c0 ? v2 : v6; r = dpp_xor1(s); v2 = (c0 ? v6 : v2) + r;
            s = c0 ? v3 : v7; r = dpp_xor1(s); v3 = (c0 ? v7 : v3) + r;
            int c1 = lane & 2;
            s = c1 ? v0 : v2; r = dpp_xor2(s); v0 = (c1 ? v2 : v0) + r;
            s = c1 ? v1 : v3; r = dpp_xor2(s); v1 = (c1 ? v3 : v1) + r;
            int c2 = lane & 4;
            s = c2 ? v0 : v1; r = __shfl_xor(s, 4, 64); v0 = (c2 ? v1 : v0) + r;
            v0 += __shfl_xor(v0, 8, 64);
            v0 += __shfl_xor(v0, 16, 64);
            v0 += __shfl_xor(v0, 32, 64);
        }
        // lane l holds S[q], q = 4*l0 + 2*l1 + l2

        if (lane < 8) {
            int qr = ((lane & 1) << 2) | (lane & 2) | ((lane >> 2) & 1);
            float a;
            if (w == 2) { float e2 = __expf(2.f * v0); a = (e2 - 1.f) / (e2 + 1.f); }
            else        { a = 1.f / (1.f + __expf(-v0)); }
            gact[w][qr] = a;
        }
        __syncthreads();

        if (tid < 8) {
            float fv = gact[0][tid], iv = gact[1][tid], gv = gact[2][tid], ov = gact[3][tid];
            float cv = csh[tid];
            cv = fv * cv + iv * gv;
            float e2 = __expf(2.f * cv);
            float hv = ov * ((e2 - 1.f) / (e2 + 1.f));
            csh[tid] = cv; hsh[tid] = hv;
            out[((size_t)t * BB + b) * NQ + tid] = hv;
        }
        __syncthreads();

        xv[0] = xn[0]; xv[1] = xn[1]; xv[2] = xn[2]; xv[3] = xn[3];
    }

    if (tid < 8) {
        hst[b * NQ + tid] = hsh[tid];
        cst[b * NQ + tid] = csh[tid];
    }
}

extern "C" void kernel_launch(void* const* d_in, const int* in_sizes, int n_in,
                              void* d_out, int out_size, void* d_ws, size_t ws_size,
                              hipStream_t stream) {
    const float* x  = (const float*)d_in[0];
    const float* Wf = (const float*)d_in[1];
    const float* bf = (const float*)d_in[2];
    const float* Pf = (const float*)d_in[3];
    const float* Wi = (const float*)d_in[4];
    const float* bi = (const float*)d_in[5];
    const float* Pi = (const float*)d_in[6];
    const float* Wg = (const float*)d_in[7];
    const float* bg = (const float*)d_in[8];
    const float* Pg = (const float*)d_in[9];
    const float* Wo = (const float*)d_in[10];
    const float* bo = (const float*)d_in[11];
    const float* Po = (const float*)d_in[12];

    float* out = (float*)d_out;
    float* hst = out + (size_t)TS * BB * NQ;
    float* cst = hst + (size_t)BB * NQ;

    qlstm_fused<<<BB, 256, 0, stream>>>(x, Wf, bf, Pf, Wi, bi, Pi,
                                        Wg, bg, Pg, Wo, bo, Po,
                                        out, hst, cst);
}

// Round 4
// 650.538 us; speedup vs baseline: 5.9310x; 1.0595x over previous
//
#include <hip/hip_runtime.h>
#include <math.h>

#define TS 256
#define BB 1024
#define NQ 8
#define INDIM 128
#define CATDIM 136

__device__ __forceinline__ float dpp_xor1(float v) {
    return __int_as_float(__builtin_amdgcn_mov_dpp(__float_as_int(v), 0xB1, 0xF, 0xF, true));
}
__device__ __forceinline__ float dpp_xor2(float v) {
    return __int_as_float(__builtin_amdgcn_mov_dpp(__float_as_int(v), 0x4E, 0xF, 0xF, true));
}
__device__ __forceinline__ float rdlane(float v, int l) {
    return __int_as_float(__builtin_amdgcn_readlane(__float_as_int(v), l));
}
__device__ __forceinline__ float rdfirst(float v) {
    return __int_as_float(__builtin_amdgcn_readfirstlane(__float_as_int(v)));
}
// barrier with LDS-only drain (skip vmcnt drain of in-flight x prefetch)
__device__ __forceinline__ void lds_barrier() {
    asm volatile("s_waitcnt lgkmcnt(0)\n\ts_barrier" ::: "memory");
}
#define CMUL(zr, zi, ar, ai, br, bi) { float _t = (ar)*(br) - (ai)*(bi); zi = (ar)*(bi) + (ai)*(br); zr = _t; }

// One block = one batch element, all T=256 steps in-kernel.
// Wave w = gate (f,i,g,o). Lane holds amps k = j*64+lane, j=0..3.
// Wire q <-> bit (7-q). Algebraic folds (verified R3):
//   - RX + RY layer-0 -> single-qubit product state
//   - CNOT chain #1 (gray code) -> folded into build selectors (hoisted)
//   - CNOT chain #2 -> folded into measurement signs (hoisted)
// Only RY layer-1 is applied explicitly.
__launch_bounds__(256, 4)
__global__ void qlstm_fused(const float* __restrict__ x,
    const float* __restrict__ Wf, const float* __restrict__ bf, const float* __restrict__ Pf,
    const float* __restrict__ Wi, const float* __restrict__ bi, const float* __restrict__ Pi,
    const float* __restrict__ Wg, const float* __restrict__ bg, const float* __restrict__ Pg,
    const float* __restrict__ Wo, const float* __restrict__ bo, const float* __restrict__ Po,
    float* __restrict__ out, float* __restrict__ hst, float* __restrict__ cst)
{
    const int b = blockIdx.x;
    const int tid = threadIdx.x;
    const int w = tid >> 6;
    const int lane = tid & 63;
    const int q = lane >> 3;
    const int kg = lane & 7;

    __shared__ float gact[4][8];
    __shared__ __align__(16) float hsh[8];
    __shared__ float csh[8];

    const float* W; const float* bias; const float* P;
    if (w == 0)      { W = Wf; bias = bf; P = Pf; }
    else if (w == 1) { W = Wi; bias = bi; P = Pi; }
    else if (w == 2) { W = Wg; bias = bg; P = Pg; }
    else             { W = Wo; bias = bo; P = Po; }

    // ---- layer-0 trig (VGPR, feeds hoisted selects); layer-1 trig -> SGPR ----
    float cp0[8], sp0[8], cp1[8], sp1[8];
    #pragma unroll
    for (int qq = 0; qq < 8; ++qq) {
        float h0 = 0.5f * P[qq];
        cp0[qq] = cosf(h0); sp0[qq] = sinf(h0);
        float h1 = 0.5f * P[8 + qq];
        cp1[qq] = rdfirst(cosf(h1)); sp1[qq] = rdfirst(sinf(h1));
    }

    // ---- weights for this lane's qubit ----
    const float* Wq = W + q * CATDIM;
    float4 wx[4];
    #pragma unroll
    for (int c4 = 0; c4 < 4; ++c4)
        wx[c4] = *(const float4*)(Wq + kg * 16 + c4 * 4);
    float wh[8];
    #pragma unroll
    for (int j = 0; j < 8; ++j) wh[j] = Wq[INDIM + j];
    const float bq = bias[q];

    // ---- lane bits ----
    const int l0 = lane & 1, l1 = (lane >> 1) & 1, l2b = (lane >> 2) & 1;
    const int l3 = (lane >> 3) & 1, l4 = (lane >> 4) & 1, l5 = (lane >> 5) & 1;
    const int s0 = l0 ^ l1, s1 = l1 ^ l2b, s2 = l2b ^ l3, s3 = l3 ^ l4, s4 = l4 ^ l5;

    // ---- hoisted build-factor values (loop-invariant selects) ----
    // factor(wire, sel): sel ? (sp0*c, -cp0*s) : (cp0*c, sp0*s)
    const float u7 = s0 ? sp0[7] : cp0[7], w7 = s0 ? -cp0[7] : sp0[7];
    const float u6 = s1 ? sp0[6] : cp0[6], w6 = s1 ? -cp0[6] : sp0[6];
    const float u5 = s2 ? sp0[5] : cp0[5], w5 = s2 ? -cp0[5] : sp0[5];
    const float u4 = s3 ? sp0[4] : cp0[4], w4_ = s3 ? -cp0[4] : sp0[4];
    const float u3 = s4 ? sp0[3] : cp0[3], w3_ = s4 ? -cp0[3] : sp0[3];
    const float uga = l5 ? sp0[2] : cp0[2], wga = l5 ? -cp0[2] : sp0[2];
    const float ugb = l5 ? cp0[2] : sp0[2], wgb = l5 ? sp0[2] : -cp0[2];
    const float c00 = cp0[0], s00 = sp0[0], c01 = cp0[1], s01 = sp0[1];

    // ---- hoisted RY1 per-lane signed sines ----
    const float sv2 = l5 ? sp1[2] : -sp1[2];
    const float sv3 = l4 ? sp1[3] : -sp1[3];
    const float sv4 = l3 ? sp1[4] : -sp1[4];
    const float sv5 = l2b ? sp1[5] : -sp1[5];
    const float sv6 = l1 ? sp1[6] : -sp1[6];
    const float sv7 = l0 ? sp1[7] : -sp1[7];

    // ---- hoisted measurement sign prefixes ----
    int pr_ = l5;            const float sg2 = pr_ ? -1.f : 1.f;
    pr_ ^= l4;               const float sg3 = pr_ ? -1.f : 1.f;
    pr_ ^= l3;               const float sg4 = pr_ ? -1.f : 1.f;
    pr_ ^= l2b;              const float sg5 = pr_ ? -1.f : 1.f;
    pr_ ^= l1;               const float sg6 = pr_ ? -1.f : 1.f;
    pr_ ^= l0;               const float sg7 = pr_ ? -1.f : 1.f;

    if (tid < 8) { hsh[tid] = 0.f; csh[tid] = 0.f; }
    __syncthreads();

    // ---- x row for t=0 + running pointer for the t+1 prefetch ----
    float4 xv[4];
    {
        const float* xr = x + (size_t)b * INDIM + kg * 16;
        #pragma unroll
        for (int c4 = 0; c4 < 4; ++c4) xv[c4] = *(const float4*)(xr + c4 * 4);
    }
    const float* xp = x + ((size_t)BB + b) * INDIM + kg * 16;   // row t=1

    for (int t = 0; t < TS; ++t) {
        // ---- x-part of angle ----
        float partial =
            xv[0].x*wx[0].x + xv[0].y*wx[0].y + xv[0].z*wx[0].z + xv[0].w*wx[0].w +
            xv[1].x*wx[1].x + xv[1].y*wx[1].y + xv[1].z*wx[1].z + xv[1].w*wx[1].w +
            xv[2].x*wx[2].x + xv[2].y*wx[2].y + xv[2].z*wx[2].z + xv[2].w*wx[2].w +
            xv[3].x*wx[3].x + xv[3].y*wx[3].y + xv[3].z*wx[3].z + xv[3].w*wx[3].w;

        // prefetch row t+1 (reloads last row harmlessly at t=TS-1)
        float4 xn[4];
        #pragma unroll
        for (int c4 = 0; c4 < 4; ++c4) xn[c4] = *(const float4*)(xp + c4 * 4);
        xp += (t < TS - 2) ? (size_t)(BB * INDIM) : 0;

        partial += dpp_xor1(partial);
        partial += dpp_xor2(partial);
        partial += __shfl_xor(partial, 4, 64);

        float4 h01 = *(const float4*)&hsh[0];
        float4 h23 = *(const float4*)&hsh[4];
        float ang = partial + bq
            + wh[0]*h01.x + wh[1]*h01.y + wh[2]*h01.z + wh[3]*h01.w
            + wh[4]*h23.x + wh[5]*h23.y + wh[6]*h23.z + wh[7]*h23.w;

        // ---- one sincos per lane (own qubit), broadcast via readlane -> SGPR ----
        float c_own, s_own;
        __sincosf(0.5f * ang, &s_own, &c_own);
        float cqs[8], sqs[8];
        #pragma unroll
        for (int qq = 0; qq < 8; ++qq) {
            cqs[qq] = rdlane(c_own, qq * 8);
            sqs[qq] = rdlane(s_own, qq * 8);
        }

        // ---- product state (RX*RY0), gray-code fold in hoisted selectors ----
        float Mr = u7 * cqs[7], Mi = w7 * sqs[7];
        { float fr = u6 * cqs[6], fi = w6 * sqs[6]; CMUL(Mr, Mi, Mr, Mi, fr, fi); }
        { float fr = u5 * cqs[5], fi = w5 * sqs[5]; CMUL(Mr, Mi, Mr, Mi, fr, fi); }
        { float fr = u4 * cqs[4], fi = w4_ * sqs[4]; CMUL(Mr, Mi, Mr, Mi, fr, fi); }
        { float fr = u3 * cqs[3], fi = w3_ * sqs[3]; CMUL(Mr, Mi, Mr, Mi, fr, fi); }
        float gar = uga * cqs[2], gai = wga * sqs[2];
        float gbr = ugb * cqs[2], gbi = wgb * sqs[2];
        float MGar, MGai, MGbr, MGbi;
        CMUL(MGar, MGai, Mr, Mi, gar, gai);
        CMUL(MGbr, MGbi, Mr, Mi, gbr, gbi);
        float a1r = c01 * cqs[1], a1i = s01 * sqs[1];
        float b1r = s01 * cqs[1], b1i = -c01 * sqs[1];
        float a0r = c00 * cqs[0], a0i = s00 * sqs[0];
        float b0r = s00 * cqs[0], b0i = -c00 * sqs[0];
        float h00r, h00i, h10r, h10i, h11r, h11i, h01r, h01i;
        CMUL(h00r, h00i, a1r, a1i, a0r, a0i);
        CMUL(h10r, h10i, b1r, b1i, a0r, a0i);
        CMUL(h11r, h11i, b1r, b1i, b0r, b0i);
        CMUL(h01r, h01i, a1r, a1i, b0r, b0i);
        float re[4], im[4];
        CMUL(re[0], im[0], MGar, MGai, h00r, h00i);
        CMUL(re[1], im[1], MGbr, MGbi, h10r, h10i);
        CMUL(re[2], im[2], MGar, MGai, h11r, h11i);
        CMUL(re[3], im[3], MGbr, MGbi, h01r, h01i);

        // ---- RY layer 1 ----
        {   // wire0 (bit7): pairs (0,2),(1,3)
            float cp = cp1[0], sp = sp1[0], tr;
            tr=re[0]; re[0]=cp*tr-sp*re[2]; re[2]=sp*tr+cp*re[2];
            tr=re[1]; re[1]=cp*tr-sp*re[3]; re[3]=sp*tr+cp*re[3];
            tr=im[0]; im[0]=cp*tr-sp*im[2]; im[2]=sp*tr+cp*im[2];
            tr=im[1]; im[1]=cp*tr-sp*im[3]; im[3]=sp*tr+cp*im[3];
        }
        {   // wire1 (bit6): pairs (0,1),(2,3)
            float cp = cp1[1], sp = sp1[1], tr;
            tr=re[0]; re[0]=cp*tr-sp*re[1]; re[1]=sp*tr+cp*re[1];
            tr=re[2]; re[2]=cp*tr-sp*re[3]; re[3]=sp*tr+cp*re[3];
            tr=im[0]; im[0]=cp*tr-sp*im[1]; im[1]=sp*tr+cp*im[1];
            tr=im[2]; im[2]=cp*tr-sp*im[3]; im[3]=sp*tr+cp*im[3];
        }
        #define RY_X(MASKOP, cp, sv)                                  \
            _Pragma("unroll")                                         \
            for (int j = 0; j < 4; ++j) {                             \
                float pr = MASKOP(re[j]);                             \
                float pi = MASKOP(im[j]);                             \
                re[j] = (cp)*re[j] + (sv)*pr;                         \
                im[j] = (cp)*im[j] + (sv)*pi;                         \
            }
        #define SH32(v) __shfl_xor(v, 32, 64)
        #define SH16(v) __shfl_xor(v, 16, 64)
        #define SH8(v)  __shfl_xor(v, 8, 64)
        #define SH4(v)  __shfl_xor(v, 4, 64)
        RY_X(SH32, cp1[2], sv2)      // wire2 (bit5)
        RY_X(SH16, cp1[3], sv3)      // wire3 (bit4)
        RY_X(SH8,  cp1[4], sv4)      // wire4 (bit3)
        RY_X(SH4,  cp1[5], sv5)      // wire5 (bit2)
        RY_X(dpp_xor2, cp1[6], sv6)  // wire6 (bit1)
        RY_X(dpp_xor1, cp1[7], sv7)  // wire7 (bit0)

        // ---- measurement, CNOT chain #2 folded into signs ----
        float p0 = re[0]*re[0] + im[0]*im[0];
        float p1 = re[1]*re[1] + im[1]*im[1];
        float p2 = re[2]*re[2] + im[2]*im[2];
        float p3 = re[3]*re[3] + im[3]*im[3];
        float v0 = (p0 + p1) - (p2 + p3);        // wire0
        float D  = (p0 - p1) - (p2 - p3);        // shared combo
        float v1 = D;
        float v2 = sg2 * D;
        float v3 = sg3 * D;
        float v4 = sg4 * D;
        float v5 = sg5 * D;
        float v6 = sg6 * D;
        float v7 = sg7 * D;

        // ---- 8-value 64-lane reduction ----
        {
            int c0 = lane & 1;
            float s, r;
            s = c0 ? v0 : v4; r = dpp_xor1(s); v0 = (c0 ? v4 : v0) + r;
            s = c0 ? v1 : v5; r = dpp_xor1(s); v1 = (c0 ? v5 : v1) + r;
            s = c0 ? v2 : v6; r = dpp_xor1(s); v2 = (c0 ? v6 : v2) + r;
            s = c0 ? v3 : v7; r = dpp_xor1(s); v3 = (c0 ? v7 : v3) + r;
            int c1 = lane & 2;
            s = c1 ? v0 : v2; r = dpp_xor2(s); v0 = (c1 ? v2 : v0) + r;
            s = c1 ? v1 : v3; r = dpp_xor2(s); v1 = (c1 ? v3 : v1) + r;
            int c2 = lane & 4;
            s = c2 ? v0 : v1; r = __shfl_xor(s, 4, 64); v0 = (c2 ? v1 : v0) + r;
            v0 += __shfl_xor(v0, 8, 64);
            v0 += __shfl_xor(v0, 16, 64);
            v0 += __shfl_xor(v0, 32, 64);
        }
        // lane l holds S[q], q = 4*l0 + 2*l1 + l2

        if (lane < 8) {
            int qr = ((lane & 1) << 2) | (lane & 2) | ((lane >> 2) & 1);
            float a;
            if (w == 2) { float e2 = __expf(2.f * v0); a = (e2 - 1.f) / (e2 + 1.f); }
            else        { a = 1.f / (1.f + __expf(-v0)); }
            gact[w][qr] = a;
        }
        lds_barrier();

        if (tid < 8) {
            float fv = gact[0][tid], iv = gact[1][tid], gv = gact[2][tid], ov = gact[3][tid];
            float cv = csh[tid];
            cv = fv * cv + iv * gv;
            float e2 = __expf(2.f * cv);
            float hv = ov * ((e2 - 1.f) / (e2 + 1.f));
            csh[tid] = cv; hsh[tid] = hv;
            out[((size_t)t * BB + b) * NQ + tid] = hv;
        }
        lds_barrier();

        xv[0] = xn[0]; xv[1] = xn[1]; xv[2] = xn[2]; xv[3] = xn[3];
    }

    if (tid < 8) {
        hst[b * NQ + tid] = hsh[tid];
        cst[b * NQ + tid] = csh[tid];
    }
}

extern "C" void kernel_launch(void* const* d_in, const int* in_sizes, int n_in,
                              void* d_out, int out_size, void* d_ws, size_t ws_size,
                              hipStream_t stream) {
    const float* x  = (const float*)d_in[0];
    const float* Wf = (const float*)d_in[1];
    const float* bf = (const float*)d_in[2];
    const float* Pf = (const float*)d_in[3];
    const float* Wi = (const float*)d_in[4];
    const float* bi = (const float*)d_in[5];
    const float* Pi = (const float*)d_in[6];
    const float* Wg = (const float*)d_in[7];
    const float* bg = (const float*)d_in[8];
    const float* Pg = (const float*)d_in[9];
    const float* Wo = (const float*)d_in[10];
    const float* bo = (const float*)d_in[11];
    const float* Po = (const float*)d_in[12];

    float* out = (float*)d_out;
    float* hst = out + (size_t)TS * BB * NQ;
    float* cst = hst + (size_t)BB * NQ;

    qlstm_fused<<<BB, 256, 0, stream>>>(x, Wf, bf, Pf, Wi, bi, Pi,
                                        Wg, bg, Pg, Wo, bo, Po,
                                        out, hst, cst);
}